// Round 1
// baseline (281.124 us; speedup 1.0000x reference)
//
#include <hip/hip_runtime.h>

// Problem constants (from reference): B=64, T=512, D=41
#define BB 64
#define TT 512
#define DD 41
#define LL (TT * DD)          // 20992
#define COLS (DD + 3)         // 44
#define NTH 1024
#define CHUNK ((LL + NTH - 1) / NTH)  // 21

// Kernel A: per-batch stable partition. One block per batch row.
// Thread i owns contiguous elements [i*CHUNK, (i+1)*CHUNK) -> stability.
// Writes inverse permutation: srcIdx[b*L + p] = (l+1) if observed, -(l+1) if padded.
__global__ __launch_bounds__(NTH)
void tf_scan_kernel(const int* __restrict__ mask, int* __restrict__ srcIdx) {
    const int b   = blockIdx.x;
    const int tid = threadIdx.x;
    const int* mrow = mask + (size_t)b * LL;
    int* srow = srcIdx + (size_t)b * LL;

    const int begin = tid * CHUNK;

    int mloc[CHUNK];
    int cnt = 0;
#pragma unroll
    for (int i = 0; i < CHUNK; ++i) {
        const int l = begin + i;
        const int m = (l < LL) ? mrow[l] : 0;
        mloc[i] = m;
        cnt += m;
    }

    __shared__ int s[NTH];
    s[tid] = cnt;
    __syncthreads();
    // Hillis–Steele inclusive scan over 1024 entries (10 steps)
    for (int off = 1; off < NTH; off <<= 1) {
        const int v = (tid >= off) ? s[tid - off] : 0;
        __syncthreads();
        s[tid] += v;
        __syncthreads();
    }
    const int nObs = s[NTH - 1];
    int eObs = s[tid] - cnt;   // exclusive count of observed before my chunk

#pragma unroll
    for (int i = 0; i < CHUNK; ++i) {
        const int l = begin + i;
        if (l >= LL) break;
        if (mloc[i]) {
            srow[eObs] = l + 1;        // observed, packed to front in l-order
            ++eObs;
        } else {
            srow[nObs + (l - eObs)] = -(l + 1);  // padded, packed to back in l-order
        }
    }
}

// Kernel B: one thread per output float4 (44 cols = 11 float4 per packed row).
// Fully coalesced full-cache-line output writes.
__global__ __launch_bounds__(256)
void tf_emit_kernel(const float* __restrict__ target_x,
                    const float* __restrict__ vals,
                    const int* __restrict__ srcIdx,
                    float* __restrict__ out,
                    int total4) {
    const int o = blockIdx.x * blockDim.x + threadIdx.x;
    if (o >= total4) return;

    const int c4 = o % 11;          // which float4 within the row
    const int pg = o / 11;          // b*L + p
    const int b  = pg / LL;

    const int raw   = srcIdx[pg];
    const bool valid = raw > 0;
    const int l  = (valid ? raw : -raw) - 1;   // source flat index in [0, L)
    const int t  = l / DD;
    const int ch = valid ? (l - t * DD) : 0;   // C_p = C * mk -> 0 when padded
    const float vm  = valid ? 1.0f : 0.0f;
    const float tau = target_x[b * TT + t] * vm;  // always-in-range load, mask after
    const float U   = vals[(size_t)b * LL + l] * vm;

    const int c0 = c4 * 4;
    float v[4];
#pragma unroll
    for (int j = 0; j < 4; ++j) {
        const int c = c0 + j;
        float x;
        if (c == 0)            x = tau;                         // tau_p
        else if (c <= DD)      x = (c - 1 == ch) ? 1.0f : 0.0f; // one_hot(C_p)
        else if (c == DD + 1)  x = U;                           // U_p
        else                   x = vm;                          // valid flag
        v[j] = x;
    }
    float4 r;
    r.x = v[0]; r.y = v[1]; r.z = v[2]; r.w = v[3];
    reinterpret_cast<float4*>(out)[o] = r;
}

extern "C" void kernel_launch(void* const* d_in, const int* in_sizes, int n_in,
                              void* d_out, int out_size, void* d_ws, size_t ws_size,
                              hipStream_t stream) {
    const float* target_x = (const float*)d_in[0];  // [B, T]
    const float* vals     = (const float*)d_in[1];  // [B, T, D]
    const int*   mask     = (const int*)d_in[2];    // [B, T, D]
    float* out = (float*)d_out;                     // [B, L, D+3]
    int* srcIdx = (int*)d_ws;                       // [B, L] ints = 5.4 MB scratch

    tf_scan_kernel<<<BB, NTH, 0, stream>>>(mask, srcIdx);

    const int total4 = BB * LL * (COLS / 4);        // 14,778,368 float4s
    const int blocks = (total4 + 255) / 256;
    tf_emit_kernel<<<blocks, 256, 0, stream>>>(target_x, vals, srcIdx, out, total4);
}

// Round 3
// 268.593 us; speedup vs baseline: 1.0467x; 1.0467x over previous
//
#include <hip/hip_runtime.h>

// Problem constants (from reference): B=64, T=512, D=41
#define BB 64
#define TT 512
#define DD 41
#define LL (TT * DD)          // 20992
#define COLS (DD + 3)         // 44
#define F4_PER_ROW (COLS / 4) // 11
#define NTH 1024
#define CHUNK ((LL + NTH - 1) / NTH)  // 21

#define ROWS 256                       // packed rows per emit block tile
#define TILES_PER_B (LL / ROWS)        // 82 (exact: 20992 = 82*256)

typedef float f4v __attribute__((ext_vector_type(4)));  // native vector (nontemporal-ok)

// ---------------------------------------------------------------------------
// Kernel A: per-batch stable partition. One block per batch row.
// Thread i owns contiguous elements [i*CHUNK, (i+1)*CHUNK) -> stability.
// Writes inverse permutation: srcIdx[b*L + p] = (l+1) if observed, -(l+1) if padded.
// (verified correct in R1; unchanged)
// ---------------------------------------------------------------------------
__global__ __launch_bounds__(NTH)
void tf_scan_kernel(const int* __restrict__ mask, int* __restrict__ srcIdx) {
    const int b   = blockIdx.x;
    const int tid = threadIdx.x;
    const int* mrow = mask + (size_t)b * LL;
    int* srow = srcIdx + (size_t)b * LL;

    const int begin = tid * CHUNK;

    int mloc[CHUNK];
    int cnt = 0;
#pragma unroll
    for (int i = 0; i < CHUNK; ++i) {
        const int l = begin + i;
        const int m = (l < LL) ? mrow[l] : 0;
        mloc[i] = m;
        cnt += m;
    }

    __shared__ int s[NTH];
    s[tid] = cnt;
    __syncthreads();
    // Hillis–Steele inclusive scan over 1024 entries (10 steps)
    for (int off = 1; off < NTH; off <<= 1) {
        const int v = (tid >= off) ? s[tid - off] : 0;
        __syncthreads();
        s[tid] += v;
        __syncthreads();
    }
    const int nObs = s[NTH - 1];
    int eObs = s[tid] - cnt;   // exclusive count of observed before my chunk

#pragma unroll
    for (int i = 0; i < CHUNK; ++i) {
        const int l = begin + i;
        if (l >= LL) break;
        if (mloc[i]) {
            srow[eObs] = l + 1;        // observed, packed to front in l-order
            ++eObs;
        } else {
            srow[nObs + (l - eObs)] = -(l + 1);  // padded, packed to back in l-order
        }
    }
}

// ---------------------------------------------------------------------------
// Kernel B: block-tiled emit. Each block owns ROWS=256 consecutive packed
// rows of one batch (tiles never cross batch: LL = 82*256).
// Phase 1: thread r resolves row pg0+r once -> {tau, U, ch, vm} in LDS (4 KB).
// Phase 2: 11 coalesced float4 NT-store sweeps; values from broadcast LDS.
// ---------------------------------------------------------------------------
__global__ __launch_bounds__(ROWS)
void tf_emit_kernel(const float* __restrict__ target_x,
                    const float* __restrict__ vals,
                    const int* __restrict__ srcIdx,
                    float* __restrict__ out) {
    __shared__ f4v info[ROWS];   // {tau, U, ch(bits), vm}

    const int blk  = blockIdx.x;
    const int b    = blk / TILES_PER_B;
    const int tile = blk - b * TILES_PER_B;
    const int pg0  = b * LL + tile * ROWS;     // global packed-row base

    // ---- phase 1: one row per thread ----
    {
        const int r   = threadIdx.x;
        const int raw = srcIdx[pg0 + r];                // coalesced
        const bool valid = raw > 0;
        const int l  = (valid ? raw : -raw) - 1;        // source flat idx in [0,L)
        const int t  = l / DD;
        const int ch = valid ? (l - t * DD) : 0;        // C_p = C*mk -> 0 when padded
        const float vm  = valid ? 1.0f : 0.0f;
        const float tau = target_x[b * TT + t] * vm;    // 2 KB table, L1-hot
        const float U   = vals[(size_t)b * LL + l] * vm;// quasi-sequential gather
        f4v inf;
        inf.x = tau; inf.y = U; inf.z = __int_as_float(ch); inf.w = vm;
        info[r] = inf;
    }
    __syncthreads();

    // ---- phase 2: 11 coalesced float4 sweeps over the 256x11 tile ----
    f4v* outp = reinterpret_cast<f4v*>(out) + (size_t)pg0 * F4_PER_ROW;
#pragma unroll
    for (int k = 0; k < F4_PER_ROW; ++k) {
        const int q  = k * ROWS + threadIdx.x;   // tile-local float4 index
        const int rr = q / F4_PER_ROW;           // row within tile (magic mul)
        const int c4 = q - rr * F4_PER_ROW;      // float4-column within row
        const f4v inf = info[rr];                // broadcast ds_read_b128
        const int ch = __float_as_int(inf.z);
        const int c0 = c4 * 4;
        f4v rv;
#pragma unroll
        for (int j = 0; j < 4; ++j) {
            const int c = c0 + j;
            float x;
            if (c == 0)            x = inf.x;                        // tau_p
            else if (c <= DD)      x = (c - 1 == ch) ? 1.0f : 0.0f;  // one_hot(C_p)
            else if (c == DD + 1)  x = inf.y;                        // U_p
            else                   x = inf.w;                        // valid flag
            rv[j] = x;
        }
        __builtin_nontemporal_store(rv, &outp[q]);
    }
}

extern "C" void kernel_launch(void* const* d_in, const int* in_sizes, int n_in,
                              void* d_out, int out_size, void* d_ws, size_t ws_size,
                              hipStream_t stream) {
    const float* target_x = (const float*)d_in[0];  // [B, T]
    const float* vals     = (const float*)d_in[1];  // [B, T, D]
    const int*   mask     = (const int*)d_in[2];    // [B, T, D]
    float* out = (float*)d_out;                     // [B, L, D+3]
    int* srcIdx = (int*)d_ws;                       // [B, L] ints = 5.4 MB scratch

    tf_scan_kernel<<<BB, NTH, 0, stream>>>(mask, srcIdx);

    const int blocks = BB * TILES_PER_B;            // 5248 tiles of 256 rows
    tf_emit_kernel<<<blocks, ROWS, 0, stream>>>(target_x, vals, srcIdx, out);
}

// Round 4
// 253.322 us; speedup vs baseline: 1.1098x; 1.0603x over previous
//
#include <hip/hip_runtime.h>

// Problem constants (from reference): B=64, T=512, D=41
#define BB 64
#define TT 512
#define DD 41
#define LL (TT * DD)          // 20992
#define COLS (DD + 3)         // 44
#define F4_PER_ROW (COLS / 4) // 11
#define NTH 1024

#define ROWS 256                       // packed rows per emit block tile
#define TILES_PER_B (LL / ROWS)        // 82 (exact: 20992 = 82*256)

typedef float f4v __attribute__((ext_vector_type(4)));  // native vector

// ---------------------------------------------------------------------------
// Kernel A: per-batch stable partition. One block per batch row.
// int4-vectorized mask loads. Exact uint4 tiling: LL/4 = 5248 int4s;
// threads 0..127 own 6 int4s (24 elems), threads 128..1023 own 5 (20 elems).
// Ownership is contiguous & ordered -> stability preserved.
// Writes inverse permutation: srcIdx[b*L+p] = (l+1) observed, -(l+1) padded.
// ---------------------------------------------------------------------------
__global__ __launch_bounds__(NTH)
void tf_scan_kernel(const int* __restrict__ mask, int* __restrict__ srcIdx) {
    const int b   = blockIdx.x;
    const int tid = threadIdx.x;
    const int* mrow = mask + (size_t)b * LL;
    int* srow = srcIdx + (size_t)b * LL;

    const bool six = tid < 128;                      // wave-uniform split (2 waves)
    const int q0 = six ? tid * 6 : 768 + (tid - 128) * 5;  // int4 base index
    const int n  = six ? 24 : 20;                    // elements owned
    const int begin = q0 * 4;                        // flat element base

    int4 m[6];
    int cnt = 0;
#pragma unroll
    for (int i = 0; i < 6; ++i) {
        if (i * 4 < n) {
            m[i] = reinterpret_cast<const int4*>(mrow)[q0 + i];
            cnt += m[i].x + m[i].y + m[i].z + m[i].w;
        }
    }

    __shared__ int s[NTH];
    s[tid] = cnt;
    __syncthreads();
    // Hillis–Steele inclusive scan over 1024 entries (10 steps) — verified R1/R3
    for (int off = 1; off < NTH; off <<= 1) {
        const int v = (tid >= off) ? s[tid - off] : 0;
        __syncthreads();
        s[tid] += v;
        __syncthreads();
    }
    const int nObs = s[NTH - 1];
    int eObs = s[tid] - cnt;   // exclusive count of observed before my chunk

#pragma unroll
    for (int i = 0; i < 24; ++i) {       // i compile-time (full unroll) -> regs
        if (i < n) {
            const int mv = (i & 3) == 0 ? m[i >> 2].x
                         : (i & 3) == 1 ? m[i >> 2].y
                         : (i & 3) == 2 ? m[i >> 2].z
                         :                m[i >> 2].w;
            const int l = begin + i;
            if (mv) {
                srow[eObs] = l + 1;                 // observed, packed front
                ++eObs;
            } else {
                srow[nObs + (l - eObs)] = -(l + 1); // padded, packed back
            }
        }
    }
}

// ---------------------------------------------------------------------------
// Kernel B: block-tiled emit. Each block owns ROWS=256 consecutive packed
// rows of one batch (tiles never cross batch: LL = 82*256).
// Phase 1: thread r resolves row pg0+r once -> {tau, U, ch, vm} in LDS (4 KB).
// Phase 2: 11 coalesced float4 PLAIN-store sweeps (NT removed — fill kernels
// prove plain streaming stores hit 6.4 TB/s).
// ---------------------------------------------------------------------------
__global__ __launch_bounds__(ROWS)
void tf_emit_kernel(const float* __restrict__ target_x,
                    const float* __restrict__ vals,
                    const int* __restrict__ srcIdx,
                    float* __restrict__ out) {
    __shared__ f4v info[ROWS];   // {tau, U, ch(bits), vm}

    const int blk  = blockIdx.x;
    const int b    = blk / TILES_PER_B;
    const int tile = blk - b * TILES_PER_B;
    const int pg0  = b * LL + tile * ROWS;     // global packed-row base

    // ---- phase 1: one row per thread ----
    {
        const int r   = threadIdx.x;
        const int raw = srcIdx[pg0 + r];                // coalesced
        const bool valid = raw > 0;
        const int l  = (valid ? raw : -raw) - 1;        // source flat idx in [0,L)
        const int t  = l / DD;
        const int ch = valid ? (l - t * DD) : 0;        // C_p = C*mk -> 0 when padded
        const float vm  = valid ? 1.0f : 0.0f;
        const float tau = target_x[b * TT + t] * vm;    // 2 KB table, L1-hot
        const float U   = vals[(size_t)b * LL + l] * vm;// quasi-sequential gather
        f4v inf;
        inf.x = tau; inf.y = U; inf.z = __int_as_float(ch); inf.w = vm;
        info[r] = inf;
    }
    __syncthreads();

    // ---- phase 2: 11 coalesced float4 sweeps over the 256x11 tile ----
    f4v* outp = reinterpret_cast<f4v*>(out) + (size_t)pg0 * F4_PER_ROW;
#pragma unroll
    for (int k = 0; k < F4_PER_ROW; ++k) {
        const int q  = k * ROWS + threadIdx.x;   // tile-local float4 index
        const int rr = q / F4_PER_ROW;           // row within tile (magic mul)
        const int c4 = q - rr * F4_PER_ROW;      // float4-column within row
        const f4v inf = info[rr];                // broadcast ds_read_b128
        const int ch = __float_as_int(inf.z);
        const int c0 = c4 * 4;
        f4v rv;
#pragma unroll
        for (int j = 0; j < 4; ++j) {
            const int c = c0 + j;
            float x;
            if (c == 0)            x = inf.x;                        // tau_p
            else if (c <= DD)      x = (c - 1 == ch) ? 1.0f : 0.0f;  // one_hot(C_p)
            else if (c == DD + 1)  x = inf.y;                        // U_p
            else                   x = inf.w;                        // valid flag
            rv[j] = x;
        }
        outp[q] = rv;                            // plain coalesced store
    }
}

extern "C" void kernel_launch(void* const* d_in, const int* in_sizes, int n_in,
                              void* d_out, int out_size, void* d_ws, size_t ws_size,
                              hipStream_t stream) {
    const float* target_x = (const float*)d_in[0];  // [B, T]
    const float* vals     = (const float*)d_in[1];  // [B, T, D]
    const int*   mask     = (const int*)d_in[2];    // [B, T, D]
    float* out = (float*)d_out;                     // [B, L, D+3]
    int* srcIdx = (int*)d_ws;                       // [B, L] ints = 5.4 MB scratch

    tf_scan_kernel<<<BB, NTH, 0, stream>>>(mask, srcIdx);

    const int blocks = BB * TILES_PER_B;            // 5248 tiles of 256 rows
    tf_emit_kernel<<<blocks, ROWS, 0, stream>>>(target_x, vals, srcIdx, out);
}

// Round 6
// 247.406 us; speedup vs baseline: 1.1363x; 1.0239x over previous
//
#include <hip/hip_runtime.h>

// Problem constants (from reference): B=64, T=512, D=41
#define BB 64
#define TT 512
#define DD 41
#define LL (TT * DD)          // 20992
#define COLS (DD + 3)         // 44
#define F4R (COLS / 4)        // 11
#define TILE 256
#define TPB (LL / TILE)       // 82 tiles per batch row (exact)
#define NTILES (BB * TPB)     // 5248

typedef float f4v __attribute__((ext_vector_type(4)));  // native vector

// Workspace layout (ints): [0,NTILES) partials | [NTILES,2*NTILES) tileOff | [2*NTILES,+BB) nObs

// ---------------------------------------------------------------------------
// K1: per-tile observed count. Flat tile index (rows are tile-aligned:
// b*LL + tile*256 == blk*256). Coalesced dword loads, ballot count.
// ---------------------------------------------------------------------------
__global__ __launch_bounds__(TILE)
void k1_count(const int* __restrict__ mask, int* __restrict__ partials) {
    const int blk = blockIdx.x;
    const int tid = threadIdx.x;
    const int m = mask[(size_t)blk * TILE + tid];
    const unsigned long long bal = __ballot(m != 0);
    __shared__ int ws[4];
    if ((tid & 63) == 0) ws[tid >> 6] = __popcll(bal);
    __syncthreads();
    if (tid == 0) partials[blk] = ws[0] + ws[1] + ws[2] + ws[3];
}

// ---------------------------------------------------------------------------
// K2: per-batch-row exclusive scan of the 82 tile counts. 64 blocks x 128.
// ---------------------------------------------------------------------------
__global__ __launch_bounds__(128)
void k2_scan(const int* __restrict__ partials, int* __restrict__ tileOff,
             int* __restrict__ nObs) {
    const int b   = blockIdx.x;
    const int tid = threadIdx.x;
    const int v = (tid < TPB) ? partials[b * TPB + tid] : 0;
    __shared__ int s[128];
    s[tid] = v;
    __syncthreads();
    for (int off = 1; off < 128; off <<= 1) {
        const int t = (tid >= off) ? s[tid - off] : 0;
        __syncthreads();
        s[tid] += t;
        __syncthreads();
    }
    if (tid < TPB) tileOff[b * TPB + tid] = s[tid] - v;   // exclusive
    if (tid == TPB - 1) nObs[b] = s[tid];                 // row total
}

// ---------------------------------------------------------------------------
// K3: fused rank + emit. Block = one contiguous SOURCE tile of 256 elems.
// All input loads coalesced (no gather). Ballot-scan gives each source elem
// its local packed rank; fields staged in LDS by local dest; 11 coalesced
// f4 store sweeps, rows split across the two contiguous dest runs.
// ---------------------------------------------------------------------------
__global__ __launch_bounds__(TILE)
void k3_emit(const float* __restrict__ target_x, const float* __restrict__ vals,
             const int* __restrict__ mask, const int* __restrict__ tileOff,
             const int* __restrict__ nObs, float* __restrict__ out) {
    const int blk = blockIdx.x;               // flat tile index
    const int tid = threadIdx.x;
    const int b     = blk / TPB;
    const int lrow0 = (blk - b * TPB) * TILE; // base index within batch row
    const size_t src = (size_t)blk * TILE + tid;

    const int   m    = mask[src] != 0;        // coalesced
    const float Uraw = vals[src];             // coalesced
    const int lrow = lrow0 + tid;
    const int t  = lrow / DD;                 // magic-mul
    const int ch = lrow - t * DD;
    const float tau = target_x[b * TT + t];   // 2 KB row table, L1-hot

    // ---- block-wide exclusive scan of m (ballot + wave sums) ----
    const unsigned long long bal = __ballot(m);
    const int lane = tid & 63;
    const int w    = tid >> 6;
    const int rankInWave = __popcll(bal & ((1ull << lane) - 1ull));
    __shared__ int wsum[4];
    if (lane == 0) wsum[w] = __popcll(bal);
    __syncthreads();
    const int s0 = wsum[0], s1 = wsum[1], s2 = wsum[2], s3 = wsum[3];
    const int cntObs = s0 + s1 + s2 + s3;
    const int wbase  = (w > 0 ? s0 : 0) + (w > 1 ? s1 : 0) + (w > 2 ? s2 : 0);
    const int eObs = wbase + rankInWave;      // exclusive obs count before tid
    const int d = m ? eObs : cntObs + (tid - eObs);  // local packed dest (perm of 0..255)

    __shared__ f4v info[TILE];                // {tau_p, U_p, ch(bits), vm}
    f4v inf;
    inf.x = m ? tau : 0.0f;
    inf.y = m ? Uraw : 0.0f;
    inf.z = __int_as_float(m ? ch : 0);
    inf.w = m ? 1.0f : 0.0f;
    info[d] = inf;
    __syncthreads();

    // ---- dest runs: observed rows then padded rows (both contiguous) ----
    const int tOff    = tileOff[blk];                  // obs before this tile (row-local)
    const int padRow0 = nObs[b] + (lrow0 - tOff);      // pads before this tile
    const size_t rowBase = (size_t)b * LL;

    f4v* outp = reinterpret_cast<f4v*>(out);
#pragma unroll
    for (int k = 0; k < F4R; ++k) {
        const int q  = k * TILE + tid;        // tile-local f4 index
        const int rr = q / F4R;               // local row
        const int c4 = q - rr * F4R;          // f4-column
        const f4v v = info[rr];               // broadcast ds_read_b128
        const int chh = __float_as_int(v.z);
        const int gr = (rr < cntObs) ? (tOff + rr) : (padRow0 + (rr - cntObs));
        const int c0 = c4 * 4;
        f4v rv;
#pragma unroll
        for (int j = 0; j < 4; ++j) {
            const int c = c0 + j;
            float x;
            if (c == 0)            x = v.x;                          // tau_p
            else if (c <= DD)      x = (c - 1 == chh) ? 1.0f : 0.0f; // one_hot(C_p)
            else if (c == DD + 1)  x = v.y;                          // U_p
            else                   x = v.w;                          // valid flag
            rv[j] = x;
        }
        outp[(rowBase + (size_t)gr) * F4R + c4] = rv;   // coalesced within runs
    }
}

extern "C" void kernel_launch(void* const* d_in, const int* in_sizes, int n_in,
                              void* d_out, int out_size, void* d_ws, size_t ws_size,
                              hipStream_t stream) {
    const float* target_x = (const float*)d_in[0];  // [B, T]
    const float* vals     = (const float*)d_in[1];  // [B, T, D]
    const int*   mask     = (const int*)d_in[2];    // [B, T, D]
    float* out = (float*)d_out;                     // [B, L, D+3]

    int* partials = (int*)d_ws;                     // [NTILES]
    int* tileOff  = partials + NTILES;              // [NTILES]
    int* nObs     = tileOff + NTILES;               // [BB]

    k1_count<<<NTILES, TILE, 0, stream>>>(mask, partials);
    k2_scan<<<BB, 128, 0, stream>>>(partials, tileOff, nObs);
    k3_emit<<<NTILES, TILE, 0, stream>>>(target_x, vals, mask, tileOff, nObs, out);
}